// Round 6
// baseline (699.950 us; speedup 1.0000x reference)
//
#include <hip/hip_runtime.h>
#include <cstdint>

#define B_ 8
#define T_ 4096
#define TP1 4097
#define IN_ 512
#define H_ 512
#define N3H 1536
#define KD 1024
// fused scan: 2 halves of T, each 32 chunks x 64 timesteps
#define HCH 32     // chunks per half
#define CLEN 64

typedef __attribute__((ext_vector_type(4))) float floatx4;
typedef __attribute__((ext_vector_type(4))) float f4;
typedef __attribute__((ext_vector_type(8))) short short8;
typedef __attribute__((ext_vector_type(4))) unsigned short us4;
typedef __attribute__((ext_vector_type(2))) _Float16 h2;

__device__ __forceinline__ unsigned short f2bf(float v){
  unsigned int u = __float_as_uint(v);
  unsigned int r = (u + 0x7fffu + ((u >> 16) & 1u)) >> 16;
  return (unsigned short)r;
}
// fast sigmoid: one v_exp_f32 + one v_rcp_f32 (no IEEE div sequence)
__device__ __forceinline__ float sigm(float x){
  return __builtin_amdgcn_rcpf(1.f + __expf(-x));
}
__device__ __forceinline__ float tanhf_(float x){ return 2.f*sigm(2.f*x) - 1.f; }

#define GLLS(src, dst) __builtin_amdgcn_global_load_lds( \
    (const __attribute__((address_space(1))) void*)(src), \
    (__attribute__((address_space(3))) void*)(dst), 16, 0, 0)

// x f32 [B,T,IN] -> xpad bf16 [B, T+1, IN] with zero row at t'=0; also zero barrier ctrs
__global__ void cast_pad_kernel(const float* __restrict__ x, unsigned short* __restrict__ xpad,
                                int* __restrict__ ctrs){
  int64_t i = (int64_t)blockIdx.x*256 + threadIdx.x;       // over B*TP1*(IN/4)
  const int64_t total = (int64_t)B_*TP1*(IN_/4);
  if (i < 4) ctrs[i] = 0;
  if (i >= total) return;
  int cg = (int)(i & 127);
  int64_t r = i >> 7;                                      // row (b*TP1 + t)
  int t = (int)(r % TP1);
  int b = (int)(r / TP1);
  us4 o;
  if (t == 0){ o = (us4){0,0,0,0}; }
  else {
    f4 v = *(const f4*)(x + ((int64_t)b*T_ + (t-1))*IN_ + cg*4);
    #pragma unroll
    for (int u=0;u<4;++u) o[u] = f2bf(v[u]);
  }
  *(us4*)(xpad + r*IN_ + cg*4) = o;
}

// w f32 [3H, IN, K=2] -> wt bf16 [3H, 1024], k-major halves; blockIdx.y picks layer
__global__ void wt_kernel(const float* __restrict__ wA, unsigned short* __restrict__ wtA,
                          const float* __restrict__ wB, unsigned short* __restrict__ wtB){
  int i = blockIdx.x*256 + threadIdx.x;                    // over N3H*512
  if (i >= N3H*512) return;
  const float* w = blockIdx.y ? wB : wA;
  unsigned short* wt = blockIdx.y ? wtB : wtA;
  int ci = i & 511;
  int o = i >> 9;
  const float* wp = w + (int64_t)o*KD + ci*2;
  wt[(int64_t)o*KD + ci]       = f2bf(wp[0]);
  wt[(int64_t)o*KD + 512 + ci] = f2bf(wp[1]);
}

// C[m][n] = act(sum_k A[m][k]*W[n][k] + bias[n]) stored f16.
// XCD-swizzled linear grid; BK=32 (m97 structure); fast rcp-based activations.
__global__ __launch_bounds__(256) void gemm_kernel(
    const unsigned short* __restrict__ A, const unsigned short* __restrict__ W,
    const float* __restrict__ bias, _Float16* __restrict__ C){
  __shared__ unsigned short As[128*32];
  __shared__ unsigned short Bs[128*32];
  const int tid = threadIdx.x;
  const int lane = tid & 63;
  const int wave = tid >> 6;
  const int bid = blockIdx.x;
  const int xcd = bid & 7;
  const int kb  = bid >> 3;              // 0..383
  const int colt = kb % 12;
  const int rowt = (kb / 12) * 8 + xcd;  // 0..255
  const int m0 = rowt * 128;
  const int n0 = colt * 128;
  const int bb = m0 / T_;                // tile fully inside one batch (128 | 4096)
  const int act = n0 >> 9;               // 0=z(tanh), 1=f(sigm), 2=o(sigm)
  const unsigned short* aSrc = A + (int64_t)(m0 + bb + (tid>>2))*IN_ + (tid&3)*8;
  const unsigned short* bSrc = W + (int64_t)(n0 + (tid>>2))*KD + (tid&3)*8;
  unsigned short* aDst = As + tid*8;
  unsigned short* bDst = Bs + tid*8;
  const int wm = wave & 1;
  const int wn = wave >> 1;
  const int l16 = lane & 15;
  const int quad = lane >> 4;
  floatx4 acc[4][4];
  #pragma unroll
  for (int i=0;i<4;i++)
    #pragma unroll
    for (int j=0;j<4;j++) acc[i][j] = (floatx4){0.f,0.f,0.f,0.f};
  const unsigned short* aLds = As + (wm*64 + l16)*32 + quad*8;
  const unsigned short* bLds = Bs + (wn*64 + l16)*32 + quad*8;

  for (int kk = 0; kk < KD; kk += 32){
    __syncthreads();
    GLLS(aSrc + kk,           aDst);
    GLLS(aSrc + 64*IN_ + kk,  aDst + 2048);
    GLLS(bSrc + kk,           bDst);
    GLLS(bSrc + 64*KD + kk,   bDst + 2048);
    __syncthreads();
    short8 af[4], bfr[4];
    #pragma unroll
    for (int i=0;i<4;i++) af[i] = *(const short8*)(aLds + i*16*32);
    #pragma unroll
    for (int j=0;j<4;j++) bfr[j] = *(const short8*)(bLds + j*16*32);
    #pragma unroll
    for (int i=0;i<4;i++)
      #pragma unroll
      for (int j=0;j<4;j++)
        acc[i][j] = __builtin_amdgcn_mfma_f32_16x16x32_bf16(af[i], bfr[j], acc[i][j], 0, 0, 0);
  }
  float bv[4];
  #pragma unroll
  for (int j=0;j<4;j++) bv[j] = bias[n0 + wn*64 + j*16 + l16];
  #pragma unroll
  for (int i=0;i<4;i++){
    int row = m0 + wm*64 + i*16 + quad*4;
    #pragma unroll
    for (int j=0;j<4;j++){
      int col = n0 + wn*64 + j*16 + l16;
      _Float16* cp = C + (int64_t)row*N3H + col;
      #pragma unroll
      for (int r=0;r<4;r++){
        float v = acc[i][j][r] + bv[j];
        v = (act == 0) ? tanhf_(v) : sigm(v);
        cp[(int64_t)r*N3H] = (_Float16)v;
      }
    }
  }
}

// Fused per-half fo-pool scan. 512 blocks x 256 threads, 1 channel/thread.
// Block -> (chunk c in [0,32), batch bq, channel-half hc). 2 blocks/CU (64KB LDS)
// => all 512 co-resident => grid spin-barrier is safe.
// pass1: read z,f; build per-t prefix (A_t,B_t) in LDS (f16); write f32 chunk aggregate.
// barrier; prefix-compose h0 from earlier chunks (+ hin carry for HALF=1).
// pass2: h_t = A_t*h0 + B_t (LDS only), read o, write output. No z,f re-read.
template<int LAYER, int HALF>
__global__ __launch_bounds__(256) void scan_fused(
    const _Float16* __restrict__ conv,
    const float* __restrict__ hin,     // HALF=1: carry from first half (ignored HALF=0)
    float* __restrict__ hout,          // HALF=0: carry buffer; HALF=1: hT slot in d_out
    float* __restrict__ carA, float* __restrict__ carB,
    unsigned short* __restrict__ xpad, float* __restrict__ outf,
    int* __restrict__ ctr){
  __shared__ h2 AB[CLEN*256];          // [t][tid] -> {A_t, B_t}
  const int tid = threadIdx.x;
  const int bid = blockIdx.x;
  const int c  = bid >> 4;             // 0..31
  const int bq = (bid >> 1) & 7;
  const int hc = bid & 1;
  const int ch = hc*256 + tid;
  const int t0 = HALF*2048 + c*CLEN;
  const _Float16* p = conv + ((int64_t)bq*T_ + t0)*N3H + ch;
  float Aa = 1.f, Bb = 0.f;
  for (int g=0; g<CLEN/8; ++g){
    float zv[8], fv[8];
    #pragma unroll
    for (int u=0;u<8;++u){
      zv[u] = (float)p[(int64_t)(g*8+u)*N3H];
      fv[u] = (float)p[(int64_t)(g*8+u)*N3H + 512];
    }
    #pragma unroll
    for (int u=0;u<8;++u){
      Aa *= fv[u];
      Bb = fv[u]*Bb + (1.f-fv[u])*zv[u];
      h2 ab; ab[0] = (_Float16)Aa; ab[1] = (_Float16)Bb;
      AB[(g*8+u)*256 + tid] = ab;
    }
  }
  carA[(c*8+bq)*512 + ch] = Aa;
  carB[(c*8+bq)*512 + ch] = Bb;
  // ---- grid barrier (all 512 blocks co-resident) ----
  __syncthreads();
  if (tid == 0){
    __threadfence();                   // release car writes
    atomicAdd(ctr, 1);
    int it = 0;
    while (__hip_atomic_load(ctr, __ATOMIC_RELAXED, __HIP_MEMORY_SCOPE_AGENT) < 512
           && it < 100000000) ++it;    // bounded: failure -> wrong answer, not hang
  }
  __syncthreads();
  __threadfence();                     // acquire
  // ---- prefix over earlier chunks ----
  float h0 = (HALF == 1) ? hin[bq*512 + ch] : 0.f;
  for (int cc=0; cc<c; ++cc)
    h0 = carA[(cc*8+bq)*512 + ch]*h0 + carB[(cc*8+bq)*512 + ch];
  // ---- pass2: outputs from LDS prefixes + o ----
  const _Float16* po = conv + ((int64_t)bq*T_ + t0)*N3H + 1024 + ch;
  for (int g=0; g<CLEN/8; ++g){
    float ov[8];
    #pragma unroll
    for (int u=0;u<8;++u) ov[u] = (float)po[(int64_t)(g*8+u)*N3H];
    #pragma unroll
    for (int u=0;u<8;++u){
      int t = g*8 + u;
      h2 ab = AB[t*256 + tid];
      float hv = (float)ab[0]*h0 + (float)ab[1];
      float oh = ov[u]*hv;
      if (LAYER == 0) xpad[((int64_t)bq*TP1 + t0 + t + 1)*IN_ + ch] = f2bf(oh);
      else            outf[((int64_t)bq*T_ + t0 + t)*H_ + ch] = oh;
    }
  }
  if (c == HCH-1)                      // end-of-half state (f32 aggregates: precise)
    hout[bq*512 + ch] = Aa*h0 + Bb;
}

extern "C" void kernel_launch(void* const* d_in, const int* in_sizes, int n_in,
                              void* d_out, int out_size, void* d_ws, size_t ws_size,
                              hipStream_t stream){
  const float* x  = (const float*)d_in[0];
  const float* w0 = (const float*)d_in[1];
  const float* b0 = (const float*)d_in[2];
  const float* w1 = (const float*)d_in[3];
  const float* b1 = (const float*)d_in[4];
  float* out = (float*)d_out;

  char* ws = (char*)d_ws;
  size_t off = 0;
  auto alloc = [&](size_t bytes)->char*{
    char* p = ws + off; off = (off + bytes + 255) & ~(size_t)255; return p; };
  unsigned short* xpad = (unsigned short*)alloc((size_t)B_*TP1*IN_*2);
  unsigned short* Wt0  = (unsigned short*)alloc((size_t)N3H*KD*2);
  unsigned short* Wt1  = (unsigned short*)alloc((size_t)N3H*KD*2);
  _Float16* conv = (_Float16*)alloc((size_t)B_*T_*N3H*2);
  float* carA[4]; float* carB[4];
  for (int i=0;i<4;++i){               // distinct car regions per (layer,half)
    carA[i] = (float*)alloc((size_t)HCH*8*512*4);
    carB[i] = (float*)alloc((size_t)HCH*8*512*4);
  }
  float* hcarry = (float*)alloc((size_t)B_*H_*4);
  int* ctrs = (int*)alloc(4*sizeof(int));
  if (off > ws_size) return;  // workspace too small -> fail loudly in validation

  float* out_main = out;
  float* h0 = out + (int64_t)B_*T_*H_;
  float* h1 = h0 + B_*H_;

  const int64_t padN = (int64_t)B_*TP1*(IN_/4);
  cast_pad_kernel<<<(int)((padN + 255)/256), 256, 0, stream>>>(x, xpad, ctrs);
  dim3 wgrid((N3H*512 + 255)/256, 2);
  wt_kernel<<<wgrid, 256, 0, stream>>>(w0, Wt0, w1, Wt1);

  const int ggrid = (N3H/128) * ((B_*T_)/128);   // 3072
  gemm_kernel<<<ggrid, 256, 0, stream>>>(xpad, Wt0, b0, conv);
  scan_fused<0,0><<<512, 256, 0, stream>>>(conv, nullptr, hcarry, carA[0], carB[0], xpad, nullptr, ctrs+0);
  scan_fused<0,1><<<512, 256, 0, stream>>>(conv, hcarry, h0,     carA[1], carB[1], xpad, nullptr, ctrs+1);

  gemm_kernel<<<ggrid, 256, 0, stream>>>(xpad, Wt1, b1, conv);
  scan_fused<1,0><<<512, 256, 0, stream>>>(conv, nullptr, hcarry, carA[2], carB[2], nullptr, out_main, ctrs+2);
  scan_fused<1,1><<<512, 256, 0, stream>>>(conv, hcarry, h1,     carA[3], carB[3], nullptr, out_main, ctrs+3);
}

// Round 7
// 468.924 us; speedup vs baseline: 1.4927x; 1.4927x over previous
//
#include <hip/hip_runtime.h>
#include <cstdint>

#define B_ 8
#define T_ 4096
#define TP1 4097
#define IN_ 512
#define H_ 512
#define N3H 1536
#define KD 1024
#define CHUNKS 128
#define CLEN 32   // T_/CHUNKS

typedef __attribute__((ext_vector_type(4))) float floatx4;
typedef __attribute__((ext_vector_type(4))) float f4;
typedef __attribute__((ext_vector_type(8))) short short8;
typedef __attribute__((ext_vector_type(4))) unsigned short us4;
typedef __attribute__((ext_vector_type(4))) _Float16 h4;

__device__ __forceinline__ unsigned short f2bf(float v){
  unsigned int u = __float_as_uint(v);
  unsigned int r = (u + 0x7fffu + ((u >> 16) & 1u)) >> 16;
  return (unsigned short)r;
}
// fast sigmoid: one v_exp_f32 + one v_rcp_f32 (no IEEE div sequence)
__device__ __forceinline__ float sigm(float x){
  return __builtin_amdgcn_rcpf(1.f + __expf(-x));
}
__device__ __forceinline__ float tanhf_(float x){ return 2.f*sigm(2.f*x) - 1.f; }

#define GLLS(src, dst) __builtin_amdgcn_global_load_lds( \
    (const __attribute__((address_space(1))) void*)(src), \
    (__attribute__((address_space(3))) void*)(dst), 16, 0, 0)

// x f32 [B,T,IN] -> xpad bf16 [B, T+1, IN] with zero row at t'=0 (causal pad)
__global__ void cast_pad_kernel(const float* __restrict__ x, unsigned short* __restrict__ xpad){
  int64_t i = (int64_t)blockIdx.x*256 + threadIdx.x;       // over B*TP1*(IN/4)
  const int64_t total = (int64_t)B_*TP1*(IN_/4);
  if (i >= total) return;
  int cg = (int)(i & 127);
  int64_t r = i >> 7;                                      // row (b*TP1 + t)
  int t = (int)(r % TP1);
  int b = (int)(r / TP1);
  us4 o;
  if (t == 0){ o = (us4){0,0,0,0}; }
  else {
    f4 v = *(const f4*)(x + ((int64_t)b*T_ + (t-1))*IN_ + cg*4);
    #pragma unroll
    for (int u=0;u<4;++u) o[u] = f2bf(v[u]);
  }
  *(us4*)(xpad + r*IN_ + cg*4) = o;
}

// w f32 [3H, IN, K=2] -> wt bf16 [3H, 1024], k-major halves; blockIdx.y picks layer
__global__ void wt_kernel(const float* __restrict__ wA, unsigned short* __restrict__ wtA,
                          const float* __restrict__ wB, unsigned short* __restrict__ wtB){
  int i = blockIdx.x*256 + threadIdx.x;                    // over N3H*512
  if (i >= N3H*512) return;
  const float* w = blockIdx.y ? wB : wA;
  unsigned short* wt = blockIdx.y ? wtB : wtA;
  int ci = i & 511;
  int o = i >> 9;
  const float* wp = w + (int64_t)o*KD + ci*2;
  wt[(int64_t)o*KD + ci]       = f2bf(wp[0]);
  wt[(int64_t)o*KD + 512 + ci] = f2bf(wp[1]);
}

// C[m][n] = act(sum_k A[m][k]*W[n][k] + bias[n]) stored f16.
// XCD-swizzled linear grid; BK=32 (m97 structure); fast rcp-based activations.
__global__ __launch_bounds__(256) void gemm_kernel(
    const unsigned short* __restrict__ A, const unsigned short* __restrict__ W,
    const float* __restrict__ bias, _Float16* __restrict__ C){
  __shared__ unsigned short As[128*32];
  __shared__ unsigned short Bs[128*32];
  const int tid = threadIdx.x;
  const int lane = tid & 63;
  const int wave = tid >> 6;
  const int bid = blockIdx.x;
  const int xcd = bid & 7;
  const int kb  = bid >> 3;              // 0..383
  const int colt = kb % 12;
  const int rowt = (kb / 12) * 8 + xcd;  // 0..255
  const int m0 = rowt * 128;
  const int n0 = colt * 128;
  const int bb = m0 / T_;                // tile fully inside one batch (128 | 4096)
  const int act = n0 >> 9;               // 0=z(tanh), 1=f(sigm), 2=o(sigm)
  const unsigned short* aSrc = A + (int64_t)(m0 + bb + (tid>>2))*IN_ + (tid&3)*8;
  const unsigned short* bSrc = W + (int64_t)(n0 + (tid>>2))*KD + (tid&3)*8;
  unsigned short* aDst = As + tid*8;
  unsigned short* bDst = Bs + tid*8;
  const int wm = wave & 1;
  const int wn = wave >> 1;
  const int l16 = lane & 15;
  const int quad = lane >> 4;
  floatx4 acc[4][4];
  #pragma unroll
  for (int i=0;i<4;i++)
    #pragma unroll
    for (int j=0;j<4;j++) acc[i][j] = (floatx4){0.f,0.f,0.f,0.f};
  const unsigned short* aLds = As + (wm*64 + l16)*32 + quad*8;
  const unsigned short* bLds = Bs + (wn*64 + l16)*32 + quad*8;

  for (int kk = 0; kk < KD; kk += 32){
    __syncthreads();
    GLLS(aSrc + kk,           aDst);
    GLLS(aSrc + 64*IN_ + kk,  aDst + 2048);
    GLLS(bSrc + kk,           bDst);
    GLLS(bSrc + 64*KD + kk,   bDst + 2048);
    __syncthreads();
    short8 af[4], bfr[4];
    #pragma unroll
    for (int i=0;i<4;i++) af[i] = *(const short8*)(aLds + i*16*32);
    #pragma unroll
    for (int j=0;j<4;j++) bfr[j] = *(const short8*)(bLds + j*16*32);
    #pragma unroll
    for (int i=0;i<4;i++)
      #pragma unroll
      for (int j=0;j<4;j++)
        acc[i][j] = __builtin_amdgcn_mfma_f32_16x16x32_bf16(af[i], bfr[j], acc[i][j], 0, 0, 0);
  }
  float bv[4];
  #pragma unroll
  for (int j=0;j<4;j++) bv[j] = bias[n0 + wn*64 + j*16 + l16];
  #pragma unroll
  for (int i=0;i<4;i++){
    int row = m0 + wm*64 + i*16 + quad*4;
    #pragma unroll
    for (int j=0;j<4;j++){
      int col = n0 + wn*64 + j*16 + l16;
      _Float16* cp = C + (int64_t)row*N3H + col;
      #pragma unroll
      for (int r=0;r<4;r++){
        float v = acc[i][j][r] + bv[j];
        v = (act == 0) ? tanhf_(v) : sigm(v);
        cp[(int64_t)r*N3H] = (_Float16)v;
      }
    }
  }
}

// phase 1: per-chunk affine composition (Aa, Bb): h_out = Aa*h_in + Bb
__global__ void scan_phase1(const _Float16* __restrict__ conv,
                            float* __restrict__ carA, float* __restrict__ carB){
  int q = blockIdx.x*256 + threadIdx.x;     // CHUNKS*8*128 = 131072
  int chg = q & 127;
  int bq = (q >> 7) & 7;
  int c  = q >> 10;
  int ch = chg*4;
  f4 Aa = {1.f,1.f,1.f,1.f}, Bb = {0.f,0.f,0.f,0.f};
  const _Float16* p = conv + ((int64_t)bq*T_ + c*CLEN)*N3H + ch;
  for (int g=0; g<CLEN/8; ++g){
    h4 zb[8], fb[8];
    #pragma unroll
    for (int u=0;u<8;++u){
      zb[u] = *(const h4*)(p + (int64_t)u*N3H);
      fb[u] = *(const h4*)(p + (int64_t)u*N3H + 512);
    }
    #pragma unroll
    for (int u=0;u<8;++u){
      #pragma unroll
      for (int v=0;v<4;++v){
        float fv = (float)fb[u][v];
        float zv = (float)zb[u][v];
        Aa[v] *= fv;
        Bb[v] = fv*Bb[v] + (1.f-fv)*zv;
      }
    }
    p += (int64_t)8*N3H;
  }
  *(f4*)(carA + (int64_t)q*4) = Aa;
  *(f4*)(carB + (int64_t)q*4) = Bb;
}

// phase 3: compose h0 inline from car arrays (L2-resident), replay chunk, write output.
// Blocks with c==CHUNKS-1 also write hT. No phase2 kernel, no hstart buffer.
template<int LAYER>
__global__ void scan_phase3(const _Float16* __restrict__ conv,
                            const float* __restrict__ carA, const float* __restrict__ carB,
                            unsigned short* __restrict__ xpad, float* __restrict__ outf,
                            float* __restrict__ hT){
  int q = blockIdx.x*256 + threadIdx.x;     // 131072
  int chg = q & 127;
  int bq = (q >> 7) & 7;
  int c  = q >> 10;                          // uniform within a block
  int ch = chg*4;
  // ---- inline prefix: h0 = fold of chunks 0..c-1 for (bq, ch) ----
  f4 h = {0.f,0.f,0.f,0.f};
  {
    int cc = 0;
    while (cc + 8 <= c){
      f4 av[8], bv[8];
      #pragma unroll
      for (int u=0;u<8;++u){
        int64_t idx = (int64_t)((cc+u)*8 + bq)*512 + ch;
        av[u] = *(const f4*)(carA + idx);
        bv[u] = *(const f4*)(carB + idx);
      }
      #pragma unroll
      for (int u=0;u<8;++u)
        #pragma unroll
        for (int v=0;v<4;++v) h[v] = av[u][v]*h[v] + bv[u][v];
      cc += 8;
    }
    for (; cc < c; ++cc){
      int64_t idx = (int64_t)(cc*8 + bq)*512 + ch;
      f4 a = *(const f4*)(carA + idx);
      f4 b = *(const f4*)(carB + idx);
      #pragma unroll
      for (int v=0;v<4;++v) h[v] = a[v]*h[v] + b[v];
    }
  }
  // ---- replay chunk, apply o*h, write ----
  const _Float16* p = conv + ((int64_t)bq*T_ + c*CLEN)*N3H + ch;
  int t = c*CLEN;
  for (int g=0; g<CLEN/8; ++g){
    h4 zb[8], fb[8], ob[8];
    #pragma unroll
    for (int u=0;u<8;++u){
      zb[u] = *(const h4*)(p + (int64_t)u*N3H);
      fb[u] = *(const h4*)(p + (int64_t)u*N3H + 512);
      ob[u] = *(const h4*)(p + (int64_t)u*N3H + 1024);
    }
    #pragma unroll
    for (int u=0;u<8;++u){
      if (LAYER == 0){
        us4 ov4;
        #pragma unroll
        for (int v=0;v<4;++v){
          float fv = (float)fb[u][v];
          h[v] = fv*h[v] + (1.f-fv)*(float)zb[u][v];
          ov4[v] = f2bf((float)ob[u][v]*h[v]);
        }
        *(us4*)(xpad + ((int64_t)bq*TP1 + t+u + 1)*IN_ + ch) = ov4;
      } else {
        f4 of4;
        #pragma unroll
        for (int v=0;v<4;++v){
          float fv = (float)fb[u][v];
          h[v] = fv*h[v] + (1.f-fv)*(float)zb[u][v];
          of4[v] = (float)ob[u][v]*h[v];
        }
        *(f4*)(outf + ((int64_t)bq*T_ + t+u)*H_ + ch) = of4;
      }
    }
    t += 8; p += (int64_t)8*N3H;
  }
  if (c == CHUNKS-1)
    *(f4*)(hT + bq*512 + ch) = h;            // final state
}

extern "C" void kernel_launch(void* const* d_in, const int* in_sizes, int n_in,
                              void* d_out, int out_size, void* d_ws, size_t ws_size,
                              hipStream_t stream){
  const float* x  = (const float*)d_in[0];
  const float* w0 = (const float*)d_in[1];
  const float* b0 = (const float*)d_in[2];
  const float* w1 = (const float*)d_in[3];
  const float* b1 = (const float*)d_in[4];
  float* out = (float*)d_out;

  char* ws = (char*)d_ws;
  size_t off = 0;
  auto alloc = [&](size_t bytes)->char*{
    char* p = ws + off; off = (off + bytes + 255) & ~(size_t)255; return p; };
  unsigned short* xpad = (unsigned short*)alloc((size_t)B_*TP1*IN_*2);
  unsigned short* Wt0  = (unsigned short*)alloc((size_t)N3H*KD*2);
  unsigned short* Wt1  = (unsigned short*)alloc((size_t)N3H*KD*2);
  _Float16* conv = (_Float16*)alloc((size_t)B_*T_*N3H*2);
  float* carA = (float*)alloc((size_t)CHUNKS*4096*4);
  float* carB = (float*)alloc((size_t)CHUNKS*4096*4);
  if (off > ws_size) return;  // workspace too small -> fail loudly in validation

  float* out_main = out;
  float* h0 = out + (int64_t)B_*T_*H_;
  float* h1 = h0 + B_*H_;

  const int64_t padN = (int64_t)B_*TP1*(IN_/4);
  cast_pad_kernel<<<(int)((padN + 255)/256), 256, 0, stream>>>(x, xpad);
  dim3 wgrid((N3H*512 + 255)/256, 2);
  wt_kernel<<<wgrid, 256, 0, stream>>>(w0, Wt0, w1, Wt1);

  const int ggrid = (N3H/128) * ((B_*T_)/128);   // 3072
  const int sgrid = (CHUNKS*8*128) / 256;        // 512
  gemm_kernel<<<ggrid, 256, 0, stream>>>(xpad, Wt0, b0, conv);
  scan_phase1<<<sgrid, 256, 0, stream>>>(conv, carA, carB);
  scan_phase3<0><<<sgrid, 256, 0, stream>>>(conv, carA, carB, xpad, nullptr, h0);

  gemm_kernel<<<ggrid, 256, 0, stream>>>(xpad, Wt1, b1, conv);
  scan_phase1<<<sgrid, 256, 0, stream>>>(conv, carA, carB);
  scan_phase3<1><<<sgrid, 256, 0, stream>>>(conv, carA, carB, nullptr, out_main, h1);
}